// Round 7
// baseline (1442.624 us; speedup 1.0000x reference)
//
#include <hip/hip_runtime.h>
#include <math.h>

#define NN 8192
#define DD 512

typedef _Float16 f16;
typedef _Float16 half8 __attribute__((ext_vector_type(8)));
typedef _Float16 half4 __attribute__((ext_vector_type(4)));
typedef float f32x4 __attribute__((ext_vector_type(4)));

typedef const __attribute__((address_space(1))) unsigned int* gptr_t;
typedef __attribute__((address_space(3))) unsigned int* lptr_t;

__device__ __forceinline__ void gload16(const void* g, void* l) {
    __builtin_amdgcn_global_load_lds((gptr_t)g, (lptr_t)l, 16, 0, 0);
}

// ---------------- CSR build ----------------
__global__ __launch_bounds__(256) void deg_kernel(const int* __restrict__ ei,
                                                  int* __restrict__ deg, int E) {
    int e = blockIdx.x * 256 + threadIdx.x;
    if (e < E) atomicAdd(&deg[ei[E + e]], 1);
}

__global__ __launch_bounds__(1024) void scan_kernel(const int* __restrict__ deg,
                                                    int* __restrict__ row_ptr) {
    __shared__ int sums[1024];
    int tid = threadIdx.x;
    int base = tid * 8;
    int local[8];
    int s = 0;
#pragma unroll
    for (int i = 0; i < 8; i++) { local[i] = s; s += deg[base + i]; }
    sums[tid] = s;
    __syncthreads();
    for (int off = 1; off < 1024; off <<= 1) {
        int v = sums[tid];
        int u = (tid >= off) ? sums[tid - off] : 0;
        __syncthreads();
        sums[tid] = v + u;
        __syncthreads();
    }
    int prev = (tid == 0) ? 0 : sums[tid - 1];
#pragma unroll
    for (int i = 0; i < 8; i++) row_ptr[base + i] = prev + local[i];
    if (tid == 1023) row_ptr[NN] = sums[1023];
}

__global__ __launch_bounds__(256) void scatter_kernel(const int* __restrict__ ei,
                                                      const int* __restrict__ row_ptr,
                                                      int* __restrict__ deg,
                                                      int* __restrict__ csr, int E) {
    int e = blockIdx.x * 256 + threadIdx.x;
    if (e < E) {
        int dst = ei[E + e];
        int src = ei[e];
        int pos = row_ptr[dst] + atomicSub(&deg[dst], 1) - 1;
        csr[pos] = src;
    }
}

// ---------------- prep: x->f16 + weight transposes + zero deg ----------------
__device__ __forceinline__ void transpose_tile(const float* __restrict__ W,
                                               f16* __restrict__ Wt,
                                               int Kw, int Nw, int bx, int by,
                                               float (*tile)[33]) {
    int n0 = bx * 32, k0 = by * 32;
    int t = threadIdx.x;
    {
        int r = t >> 3, cq = (t & 7) * 4;
        float4 v = *(const float4*)(W + (size_t)(k0 + r) * Nw + n0 + cq);
        tile[r][cq] = v.x; tile[r][cq + 1] = v.y; tile[r][cq + 2] = v.z; tile[r][cq + 3] = v.w;
    }
    __syncthreads();
    {
        int n = t >> 3, rq = (t & 7) * 4;
        half4 h;
        h[0] = (f16)tile[rq][n];     h[1] = (f16)tile[rq + 1][n];
        h[2] = (f16)tile[rq + 2][n]; h[3] = (f16)tile[rq + 3][n];
        *(half4*)(Wt + (size_t)(n0 + n) * Kw + k0 + rq) = h;
    }
}

__global__ __launch_bounds__(256) void prep_kernel(const float* __restrict__ x,
                                                   f16* __restrict__ xh,
                                                   const float* __restrict__ W_l, f16* __restrict__ Wlt,
                                                   const float* __restrict__ W_r, f16* __restrict__ Wrt,
                                                   const float* __restrict__ Wa,  f16* __restrict__ Wat,
                                                   const float* __restrict__ W1,  f16* __restrict__ W1t,
                                                   int* __restrict__ deg) {
    __shared__ float tile[32][33];
    int b = blockIdx.x;
    if (b < 2048) {
        int i = b * 256 + threadIdx.x;
        const float4* p = (const float4*)x + (size_t)i * 2;
        float4 v0 = p[0], v1 = p[1];
        half8 h;
        h[0] = (f16)v0.x; h[1] = (f16)v0.y; h[2] = (f16)v0.z; h[3] = (f16)v0.w;
        h[4] = (f16)v1.x; h[5] = (f16)v1.y; h[6] = (f16)v1.z; h[7] = (f16)v1.w;
        ((half8*)xh)[i] = h;
        return;
    }
    b -= 2048;
    if (b < 256)      { transpose_tile(W_l, Wlt, 512, 512, b & 15, b >> 4, tile); return; }
    b -= 256;
    if (b < 256)      { transpose_tile(W_r, Wrt, 512, 512, b & 15, b >> 4, tile); return; }
    b -= 256;
    if (b < 128)      { transpose_tile(Wa, Wat, 512, 256, b & 7, b >> 3, tile); return; }
    b -= 128;
    if (b < 32)       { transpose_tile(W1, W1t, 256, 128, b & 3, b >> 2, tile); return; }
    b -= 32;
    deg[b * 256 + threadIdx.x] = 0;
}

// ---------------- mean aggregation, AMPLIFIED x32 for measurement ----------------
#define AGG_REPS 32
__global__ __launch_bounds__(256) void agg_kernel(const f16* __restrict__ xh,
                                                  const int* __restrict__ row_ptr,
                                                  const int* __restrict__ csr,
                                                  f16* __restrict__ aggh) {
    int node = blockIdx.x * 4 + (threadIdx.x >> 6);
    int l = threadIdx.x & 63;
    int s = row_ptr[node], e = row_ptr[node + 1];
    const half8* xb = (const half8*)xh;
    float acc[8] = {0, 0, 0, 0, 0, 0, 0, 0};
    for (int rep = 0; rep < AGG_REPS; ++rep) {
        int p = s;
        for (; p + 4 <= e; p += 4) {
            int s0 = csr[p], s1 = csr[p + 1], s2 = csr[p + 2], s3 = csr[p + 3];
            half8 v0 = xb[(size_t)s0 * 64 + l];
            half8 v1 = xb[(size_t)s1 * 64 + l];
            half8 v2 = xb[(size_t)s2 * 64 + l];
            half8 v3 = xb[(size_t)s3 * 64 + l];
#pragma unroll
            for (int j = 0; j < 8; j++)
                acc[j] += (float)v0[j] + (float)v1[j] + (float)v2[j] + (float)v3[j];
        }
        for (; p < e; p++) {
            half8 v = xb[(size_t)csr[p] * 64 + l];
#pragma unroll
            for (int j = 0; j < 8; j++) acc[j] += (float)v[j];
        }
        asm volatile("" ::: "memory");   // prevent rep-folding
    }
    float inv = (1.0f / AGG_REPS) / fmaxf((float)(e - s), 1.0f);
    half8 h;
#pragma unroll
    for (int j = 0; j < 8; j++) h[j] = (f16)(acc[j] * inv);
    ((half8*)aggh)[(size_t)node * 64 + l] = h;
}

// ---------------- MFMA GEMM, thin-row, AMPLIFIED xREPS for measurement ----------------
template<int BN, int REPS>
__global__ __launch_bounds__(256) void gemm_thin(const f16* __restrict__ A1,
                                                 const f16* __restrict__ B1,
                                                 const f16* __restrict__ A2,
                                                 const f16* __restrict__ B2,
                                                 const float* __restrict__ bias,
                                                 f16* __restrict__ C,
                                                 int N, int K, int relu) {
    constexpr int BM = 32;
    constexpr int FM = 2;
    constexpr int FN = BN / 64;
    constexpr int ACH = BM / 16;
    constexpr int NCH = (BM + BN) / 16;
    __shared__ f16 As[2][BM * 32];
    __shared__ f16 Bs[2][BN * 32];

    const int tid = threadIdx.x;
    const int l = tid & 63;
    const int wid = tid >> 6;
    const int row0 = blockIdx.y * BM;
    const int col0 = blockIdx.x * BN;
    const int rowc = l >> 2;
    const int sp = l & 3;

    f32x4 acc[FM][FN];
#pragma unroll
    for (int i = 0; i < FM; i++)
#pragma unroll
        for (int j = 0; j < FN; j++)
#pragma unroll
            for (int q = 0; q < 4; q++) acc[i][j][q] = 0.0f;

    const int ktiles = K >> 5;
    const int npass = (A2 != nullptr) ? 2 : 1;
    const int nt = ktiles * npass;

    auto stage = [&](int buf, int t) {
        int pass = (t >= ktiles) ? 1 : 0;
        int kk = (t - pass * ktiles) << 5;
        const f16* Ag = pass ? A2 : A1;
        const f16* Bg = pass ? B2 : B1;
#pragma unroll
        for (int c = wid; c < NCH; c += 4) {
            bool isA = (c < ACH);
            int cc = isA ? c : c - ACH;
            int row = cc * 16 + rowc;
            int slot = sp ^ ((row >> 1) & 3);
            const f16* g;
            f16* ld;
            if (isA) {
                g = Ag + (size_t)(row0 + row) * K + kk + slot * 8;
                ld = &As[buf][cc * 512];
            } else {
                g = Bg + (size_t)(col0 + row) * K + kk + slot * 8;
                ld = &Bs[buf][cc * 512];
            }
            gload16(g, ld);
        }
    };

    for (int rep = 0; rep < REPS; ++rep) {
        stage(0, 0);
        __syncthreads();
        for (int t = 0; t < nt; ++t) {
            int cur = t & 1;
            if (t + 1 < nt) stage(cur ^ 1, t + 1);
            half8 af[FM], bf[FN];
#pragma unroll
            for (int i = 0; i < FM; i++) {
                int r = i * 16 + (l & 15);
                int off = r * 64 + ((((l >> 4) ^ ((r >> 1) & 3))) << 4);
                af[i] = *(const half8*)((const char*)As[cur] + off);
            }
#pragma unroll
            for (int j = 0; j < FN; j++) {
                int r = wid * FN * 16 + j * 16 + (l & 15);
                int off = r * 64 + ((((l >> 4) ^ ((r >> 1) & 3))) << 4);
                bf[j] = *(const half8*)((const char*)Bs[cur] + off);
            }
#pragma unroll
            for (int i = 0; i < FM; i++)
#pragma unroll
                for (int j = 0; j < FN; j++)
                    acc[i][j] = __builtin_amdgcn_mfma_f32_16x16x32_f16(af[i], bf[j], acc[i][j], 0, 0, 0);
            __syncthreads();
        }
        asm volatile("" ::: "memory");
    }

    constexpr float rscale = 1.0f / REPS;
#pragma unroll
    for (int i = 0; i < FM; i++)
#pragma unroll
        for (int j = 0; j < FN; j++) {
            int row = row0 + i * 16 + ((l >> 4) << 2);
            int col = col0 + wid * FN * 16 + j * 16 + (l & 15);
            float bv = bias[col];
#pragma unroll
            for (int q = 0; q < 4; q++) {
                float v = acc[i][j][q] * rscale + bv;
                if (relu) v = fmaxf(v, 0.0f);
                C[(size_t)(row + q) * N + col] = (f16)v;
            }
        }
}

// ---------------- fused tail (unchanged) ----------------
__global__ __launch_bounds__(256) void tail_kernel(const f16* __restrict__ h3,
                                                   const float* __restrict__ W2,
                                                   const float* __restrict__ b2,
                                                   const float* __restrict__ W3,
                                                   const float* __restrict__ b3,
                                                   float* __restrict__ y) {
    int tid = blockIdx.x * 256 + threadIdx.x;
    int row = tid >> 1;
    int c0 = (tid & 1) * 32;
    float acc[32];
#pragma unroll
    for (int c = 0; c < 32; c++) acc[c] = b2[c0 + c];
    const half8* hr = (const half8*)(h3 + (size_t)row * 128);
#pragma unroll
    for (int g = 0; g < 16; g++) {
        half8 hv = hr[g];
#pragma unroll
        for (int j = 0; j < 8; j++) {
            float v = (float)hv[j];
            const float4* w = (const float4*)(W2 + (size_t)(g * 8 + j) * 64 + c0);
#pragma unroll
            for (int q = 0; q < 8; q++) {
                float4 wv = w[q];
                acc[q * 4 + 0] += v * wv.x;
                acc[q * 4 + 1] += v * wv.y;
                acc[q * 4 + 2] += v * wv.z;
                acc[q * 4 + 3] += v * wv.w;
            }
        }
    }
    float a0 = 0.f, a1 = 0.f, a2 = 0.f;
#pragma unroll
    for (int c = 0; c < 32; c++) {
        float v = fmaxf(acc[c], 0.0f);
        int k = c0 + c;
        a0 += v * W3[k * 3 + 0];
        a1 += v * W3[k * 3 + 1];
        a2 += v * W3[k * 3 + 2];
    }
    a0 += __shfl_xor(a0, 1);
    a1 += __shfl_xor(a1, 1);
    a2 += __shfl_xor(a2, 1);
    if ((tid & 1) == 0)
        ((float4*)y)[row] = make_float4(a0 + b3[0], a1 + b3[1], a2 + b3[2], 0.0f);
}

// ---------------- cdist, AMPLIFIED x4 for measurement ----------------
#define CDIST_REPS 4
__global__ __launch_bounds__(256) void cdist_kernel(const float* __restrict__ y4,
                                                    float* __restrict__ out) {
    int tx = threadIdx.x & 63;
    int ty = threadIdx.x >> 6;
    int j0 = blockIdx.x * 256 + tx * 4;
    int i0 = blockIdx.y * 64 + ty * 16;
    const float4* yv = (const float4*)y4;
    for (int rep = 0; rep < CDIST_REPS; ++rep) {
        float jx[4], jy[4], jz[4];
#pragma unroll
        for (int j = 0; j < 4; j++) {
            float4 t = yv[j0 + j];
            jx[j] = t.x; jy[j] = t.y; jz[j] = t.z;
        }
#pragma unroll
        for (int i = 0; i < 16; i++) {
            float4 ti = yv[i0 + i];
            f32x4 o;
#pragma unroll
            for (int j = 0; j < 4; j++) {
                float dx = ti.x - jx[j];
                float dy = ti.y - jy[j];
                float dz = ti.z - jz[j];
                o[j] = sqrtf(dx * dx + dy * dy + dz * dz);
            }
            __builtin_nontemporal_store(o, (f32x4*)(out + (size_t)(i0 + i) * NN + j0));
        }
        asm volatile("" ::: "memory");
    }
}

extern "C" void kernel_launch(void* const* d_in, const int* in_sizes, int n_in,
                              void* d_out, int out_size, void* d_ws, size_t ws_size,
                              hipStream_t stream) {
    const float* x   = (const float*)d_in[0];
    const int*   ei  = (const int*)d_in[1];
    const float* W_l = (const float*)d_in[2];
    const float* b_l = (const float*)d_in[3];
    const float* W_r = (const float*)d_in[4];
    const float* Wa  = (const float*)d_in[5];
    const float* ba  = (const float*)d_in[6];
    const float* W1  = (const float*)d_in[7];
    const float* b1  = (const float*)d_in[8];
    const float* W2  = (const float*)d_in[9];
    const float* b2  = (const float*)d_in[10];
    const float* W3  = (const float*)d_in[11];
    const float* b3  = (const float*)d_in[12];
    float* out = (float*)d_out;
    const int E = in_sizes[1] / 2;

    auto al = [](size_t b) { return (b + 255) & ~(size_t)255; };
    const size_t small_need = al(NN * 4) + al((NN + 1) * 4) +
                              al((size_t)E * 4) + al((size_t)NN * 16) +
                              al(512 * 512 * 2) * 2 + al(512 * 256 * 2) +
                              al(256 * 128 * 2);
    const size_t act_need = al((size_t)NN * 512 * 2) * 2 + al((size_t)NN * 512 * 2) +
                            al((size_t)NN * 256 * 2) + al((size_t)NN * 128 * 2);
    char* sbase;
    char* abase;
    if (ws_size >= small_need + act_need) {
        sbase = (char*)d_ws; abase = (char*)d_ws + small_need;
    } else if (ws_size >= small_need) {
        sbase = (char*)d_ws; abase = (char*)d_out;
    } else {
        sbase = (char*)d_out; abase = (char*)d_out + small_need;
    }
    size_t so = 0, ao = 0;
    auto carve_s = [&](size_t b) { char* p = sbase + so; so += al(b); return p; };
    auto carve_a = [&](size_t b) { char* p = abase + ao; ao += al(b); return p; };

    int*   deg     = (int*)carve_s(NN * 4);
    int*   row_ptr = (int*)carve_s((NN + 1) * 4);
    int*   csr     = (int*)carve_s((size_t)E * 4);
    float* yv      = (float*)carve_s((size_t)NN * 16);
    f16*   Wlt     = (f16*)carve_s(512 * 512 * 2);
    f16*   Wrt     = (f16*)carve_s(512 * 512 * 2);
    f16*   Wat     = (f16*)carve_s(512 * 256 * 2);
    f16*   W1t     = (f16*)carve_s(256 * 128 * 2);

    f16* x_h   = (f16*)carve_a((size_t)NN * 512 * 2);
    f16* agg_h = (f16*)carve_a((size_t)NN * 512 * 2);
    f16* h1    = (f16*)carve_a((size_t)NN * 512 * 2);
    f16* h2    = (f16*)carve_a((size_t)NN * 256 * 2);
    f16* h3    = (f16*)carve_a((size_t)NN * 128 * 2);

    // ---- prep ----
    prep_kernel<<<2048 + 256 + 256 + 128 + 32 + 32, 256, 0, stream>>>(
        x, x_h, W_l, Wlt, W_r, Wrt, Wa, Wat, W1, W1t, deg);

    // ---- CSR build ----
    deg_kernel<<<(E + 255) / 256, 256, 0, stream>>>(ei, deg, E);
    scan_kernel<<<1, 1024, 0, stream>>>(deg, row_ptr);
    scatter_kernel<<<(E + 255) / 256, 256, 0, stream>>>(ei, row_ptr, deg, csr, E);

    // ---- aggregation (x32 amplified) ----
    agg_kernel<<<NN / 4, 256, 0, stream>>>(x_h, row_ptr, csr, agg_h);

    // ---- MLP chain (amplified) ----
    gemm_thin<256, 16><<<dim3(2, 256), 256, 0, stream>>>(
        agg_h, Wlt, x_h, Wrt, b_l, h1, 512, 512, 1);
    gemm_thin<128, 32><<<dim3(2, 256), 256, 0, stream>>>(
        h1, Wat, nullptr, nullptr, ba, h2, 256, 512, 1);
    gemm_thin<128, 64><<<dim3(1, 256), 256, 0, stream>>>(
        h2, W1t, nullptr, nullptr, b1, h3, 128, 256, 1);
    // h4 + y fused (VALU)
    tail_kernel<<<NN * 2 / 256, 256, 0, stream>>>(h3, W2, b2, W3, b3, yv);

    // ---- cdist (x4 amplified) ----
    cdist_kernel<<<dim3(NN / 256, NN / 64), 256, 0, stream>>>(yv, out);
}

// Round 8
// 925.808 us; speedup vs baseline: 1.5582x; 1.5582x over previous
//
#include <hip/hip_runtime.h>
#include <math.h>

#define NN 8192
#define DD 512

typedef _Float16 f16;
typedef _Float16 half8 __attribute__((ext_vector_type(8)));
typedef _Float16 half4 __attribute__((ext_vector_type(4)));
typedef float f32x4 __attribute__((ext_vector_type(4)));

typedef const __attribute__((address_space(1))) unsigned int* gptr_t;
typedef __attribute__((address_space(3))) unsigned int* lptr_t;

__device__ __forceinline__ void gload16(const void* g, void* l) {
    __builtin_amdgcn_global_load_lds((gptr_t)g, (lptr_t)l, 16, 0, 0);
}

// ---------------- CSR build ----------------
// AMPLIFIED x32: reps 0..30 hit scratch (same contention pattern), rep 31 = real.
#define DEG_REPS 32
__global__ __launch_bounds__(256) void deg_kernel(const int* __restrict__ ei,
                                                  int* __restrict__ deg,
                                                  int* __restrict__ scratch, int E) {
    int e = blockIdx.x * 256 + threadIdx.x;
    if (e < E) {
        int dst = ei[E + e];
        for (int rep = 0; rep < DEG_REPS - 1; ++rep) {
            atomicAdd(&scratch[dst], 1);
            asm volatile("" ::: "memory");
        }
        atomicAdd(&deg[dst], 1);
    }
}

// AMPLIFIED x64 (idempotent: same row_ptr rewritten)
#define SCAN_REPS 64
__global__ __launch_bounds__(1024) void scan_kernel(const int* __restrict__ deg,
                                                    int* __restrict__ row_ptr) {
    __shared__ int sums[1024];
    int tid = threadIdx.x;
    int base = tid * 8;
    for (int rep = 0; rep < SCAN_REPS; ++rep) {
        int local[8];
        int s = 0;
#pragma unroll
        for (int i = 0; i < 8; i++) { local[i] = s; s += deg[base + i]; }
        sums[tid] = s;
        __syncthreads();
        for (int off = 1; off < 1024; off <<= 1) {
            int v = sums[tid];
            int u = (tid >= off) ? sums[tid - off] : 0;
            __syncthreads();
            sums[tid] = v + u;
            __syncthreads();
        }
        int prev = (tid == 0) ? 0 : sums[tid - 1];
#pragma unroll
        for (int i = 0; i < 8; i++) row_ptr[base + i] = prev + local[i];
        if (tid == 1023) row_ptr[NN] = sums[1023];
        asm volatile("" ::: "memory");
        __syncthreads();
    }
}

__global__ __launch_bounds__(256) void scatter_kernel(const int* __restrict__ ei,
                                                      const int* __restrict__ row_ptr,
                                                      int* __restrict__ deg,
                                                      int* __restrict__ csr, int E) {
    int e = blockIdx.x * 256 + threadIdx.x;
    if (e < E) {
        int dst = ei[E + e];
        int src = ei[e];
        int pos = row_ptr[dst] + atomicSub(&deg[dst], 1) - 1;
        csr[pos] = src;
    }
}

// ---------------- prep, AMPLIFIED x24 ----------------
#define PREP_REPS 24
__device__ __forceinline__ void transpose_tile(const float* __restrict__ W,
                                               f16* __restrict__ Wt,
                                               int Kw, int Nw, int bx, int by,
                                               float (*tile)[33]) {
    int n0 = bx * 32, k0 = by * 32;
    int t = threadIdx.x;
    {
        int r = t >> 3, cq = (t & 7) * 4;
        float4 v = *(const float4*)(W + (size_t)(k0 + r) * Nw + n0 + cq);
        tile[r][cq] = v.x; tile[r][cq + 1] = v.y; tile[r][cq + 2] = v.z; tile[r][cq + 3] = v.w;
    }
    __syncthreads();
    {
        int n = t >> 3, rq = (t & 7) * 4;
        half4 h;
        h[0] = (f16)tile[rq][n];     h[1] = (f16)tile[rq + 1][n];
        h[2] = (f16)tile[rq + 2][n]; h[3] = (f16)tile[rq + 3][n];
        *(half4*)(Wt + (size_t)(n0 + n) * Kw + k0 + rq) = h;
    }
}

__global__ __launch_bounds__(256) void prep_kernel(const float* __restrict__ x,
                                                   f16* __restrict__ xh,
                                                   const float* __restrict__ W_l, f16* __restrict__ Wlt,
                                                   const float* __restrict__ W_r, f16* __restrict__ Wrt,
                                                   const float* __restrict__ Wa,  f16* __restrict__ Wat,
                                                   const float* __restrict__ W1,  f16* __restrict__ W1t,
                                                   int* __restrict__ deg) {
    __shared__ float tile[32][33];
    for (int rep = 0; rep < PREP_REPS; ++rep) {
        int b = blockIdx.x;
        if (b < 2048) {
            int i = b * 256 + threadIdx.x;
            const float4* p = (const float4*)x + (size_t)i * 2;
            float4 v0 = p[0], v1 = p[1];
            half8 h;
            h[0] = (f16)v0.x; h[1] = (f16)v0.y; h[2] = (f16)v0.z; h[3] = (f16)v0.w;
            h[4] = (f16)v1.x; h[5] = (f16)v1.y; h[6] = (f16)v1.z; h[7] = (f16)v1.w;
            ((half8*)xh)[i] = h;
        } else {
            b -= 2048;
            if (b < 256)      { transpose_tile(W_l, Wlt, 512, 512, b & 15, b >> 4, tile); }
            else if (b < 512) { int c = b - 256; transpose_tile(W_r, Wrt, 512, 512, c & 15, c >> 4, tile); }
            else if (b < 640) { int c = b - 512; transpose_tile(Wa, Wat, 512, 256, c & 7, c >> 3, tile); }
            else if (b < 672) { int c = b - 640; transpose_tile(W1, W1t, 256, 128, c & 3, c >> 2, tile); }
            else              { int c = b - 672; deg[c * 256 + threadIdx.x] = 0; }
        }
        asm volatile("" ::: "memory");
        __syncthreads();
    }
}

// ---------------- mean aggregation (round-6 version, x1) ----------------
__global__ __launch_bounds__(256) void agg_kernel(const f16* __restrict__ xh,
                                                  const int* __restrict__ row_ptr,
                                                  const int* __restrict__ csr,
                                                  f16* __restrict__ aggh) {
    int node = blockIdx.x * 4 + (threadIdx.x >> 6);
    int l = threadIdx.x & 63;
    int s = row_ptr[node], e = row_ptr[node + 1];
    const half8* xb = (const half8*)xh;
    float acc[8] = {0, 0, 0, 0, 0, 0, 0, 0};
    int p = s;
    for (; p + 4 <= e; p += 4) {
        int s0 = csr[p], s1 = csr[p + 1], s2 = csr[p + 2], s3 = csr[p + 3];
        half8 v0 = xb[(size_t)s0 * 64 + l];
        half8 v1 = xb[(size_t)s1 * 64 + l];
        half8 v2 = xb[(size_t)s2 * 64 + l];
        half8 v3 = xb[(size_t)s3 * 64 + l];
#pragma unroll
        for (int j = 0; j < 8; j++)
            acc[j] += (float)v0[j] + (float)v1[j] + (float)v2[j] + (float)v3[j];
    }
    for (; p < e; p++) {
        half8 v = xb[(size_t)csr[p] * 64 + l];
#pragma unroll
        for (int j = 0; j < 8; j++) acc[j] += (float)v[j];
    }
    float inv = 1.0f / fmaxf((float)(e - s), 1.0f);
    half8 h;
#pragma unroll
    for (int j = 0; j < 8; j++) h[j] = (f16)(acc[j] * inv);
    ((half8*)aggh)[(size_t)node * 64 + l] = h;
}

// ---------------- MFMA GEMM thin-row (round-6 version, x1) ----------------
template<int BN>
__global__ __launch_bounds__(256) void gemm_thin(const f16* __restrict__ A1,
                                                 const f16* __restrict__ B1,
                                                 const f16* __restrict__ A2,
                                                 const f16* __restrict__ B2,
                                                 const float* __restrict__ bias,
                                                 f16* __restrict__ C,
                                                 int N, int K, int relu) {
    constexpr int BM = 32;
    constexpr int FM = 2;
    constexpr int FN = BN / 64;
    constexpr int ACH = BM / 16;
    constexpr int NCH = (BM + BN) / 16;
    __shared__ f16 As[2][BM * 32];
    __shared__ f16 Bs[2][BN * 32];

    const int tid = threadIdx.x;
    const int l = tid & 63;
    const int wid = tid >> 6;
    const int row0 = blockIdx.y * BM;
    const int col0 = blockIdx.x * BN;
    const int rowc = l >> 2;
    const int sp = l & 3;

    f32x4 acc[FM][FN];
#pragma unroll
    for (int i = 0; i < FM; i++)
#pragma unroll
        for (int j = 0; j < FN; j++)
#pragma unroll
            for (int q = 0; q < 4; q++) acc[i][j][q] = 0.0f;

    const int ktiles = K >> 5;
    const int npass = (A2 != nullptr) ? 2 : 1;
    const int nt = ktiles * npass;

    auto stage = [&](int buf, int t) {
        int pass = (t >= ktiles) ? 1 : 0;
        int kk = (t - pass * ktiles) << 5;
        const f16* Ag = pass ? A2 : A1;
        const f16* Bg = pass ? B2 : B1;
#pragma unroll
        for (int c = wid; c < NCH; c += 4) {
            bool isA = (c < ACH);
            int cc = isA ? c : c - ACH;
            int row = cc * 16 + rowc;
            int slot = sp ^ ((row >> 1) & 3);
            const f16* g;
            f16* ld;
            if (isA) {
                g = Ag + (size_t)(row0 + row) * K + kk + slot * 8;
                ld = &As[buf][cc * 512];
            } else {
                g = Bg + (size_t)(col0 + row) * K + kk + slot * 8;
                ld = &Bs[buf][cc * 512];
            }
            gload16(g, ld);
        }
    };

    stage(0, 0);
    __syncthreads();
    for (int t = 0; t < nt; ++t) {
        int cur = t & 1;
        if (t + 1 < nt) stage(cur ^ 1, t + 1);
        half8 af[FM], bf[FN];
#pragma unroll
        for (int i = 0; i < FM; i++) {
            int r = i * 16 + (l & 15);
            int off = r * 64 + ((((l >> 4) ^ ((r >> 1) & 3))) << 4);
            af[i] = *(const half8*)((const char*)As[cur] + off);
        }
#pragma unroll
        for (int j = 0; j < FN; j++) {
            int r = wid * FN * 16 + j * 16 + (l & 15);
            int off = r * 64 + ((((l >> 4) ^ ((r >> 1) & 3))) << 4);
            bf[j] = *(const half8*)((const char*)Bs[cur] + off);
        }
#pragma unroll
        for (int i = 0; i < FM; i++)
#pragma unroll
            for (int j = 0; j < FN; j++)
                acc[i][j] = __builtin_amdgcn_mfma_f32_16x16x32_f16(af[i], bf[j], acc[i][j], 0, 0, 0);
        __syncthreads();
    }

#pragma unroll
    for (int i = 0; i < FM; i++)
#pragma unroll
        for (int j = 0; j < FN; j++) {
            int row = row0 + i * 16 + ((l >> 4) << 2);
            int col = col0 + wid * FN * 16 + j * 16 + (l & 15);
            float bv = bias[col];
#pragma unroll
            for (int q = 0; q < 4; q++) {
                float v = acc[i][j][q] + bv;
                if (relu) v = fmaxf(v, 0.0f);
                C[(size_t)(row + q) * N + col] = (f16)v;
            }
        }
}

// ---------------- fused tail, AMPLIFIED x20 ----------------
#define TAIL_REPS 20
__global__ __launch_bounds__(256) void tail_kernel(const f16* __restrict__ h3,
                                                   const float* __restrict__ W2,
                                                   const float* __restrict__ b2,
                                                   const float* __restrict__ W3,
                                                   const float* __restrict__ b3,
                                                   float* __restrict__ y) {
    int tid = blockIdx.x * 256 + threadIdx.x;
    int row = tid >> 1;
    int c0 = (tid & 1) * 32;
    for (int rep = 0; rep < TAIL_REPS; ++rep) {
        float acc[32];
#pragma unroll
        for (int c = 0; c < 32; c++) acc[c] = b2[c0 + c];
        const half8* hr = (const half8*)(h3 + (size_t)row * 128);
#pragma unroll
        for (int g = 0; g < 16; g++) {
            half8 hv = hr[g];
#pragma unroll
            for (int j = 0; j < 8; j++) {
                float v = (float)hv[j];
                const float4* w = (const float4*)(W2 + (size_t)(g * 8 + j) * 64 + c0);
#pragma unroll
                for (int q = 0; q < 8; q++) {
                    float4 wv = w[q];
                    acc[q * 4 + 0] += v * wv.x;
                    acc[q * 4 + 1] += v * wv.y;
                    acc[q * 4 + 2] += v * wv.z;
                    acc[q * 4 + 3] += v * wv.w;
                }
            }
        }
        float a0 = 0.f, a1 = 0.f, a2 = 0.f;
#pragma unroll
        for (int c = 0; c < 32; c++) {
            float v = fmaxf(acc[c], 0.0f);
            int k = c0 + c;
            a0 += v * W3[k * 3 + 0];
            a1 += v * W3[k * 3 + 1];
            a2 += v * W3[k * 3 + 2];
        }
        a0 += __shfl_xor(a0, 1);
        a1 += __shfl_xor(a1, 1);
        a2 += __shfl_xor(a2, 1);
        if ((tid & 1) == 0)
            ((float4*)y)[row] = make_float4(a0 + b3[0], a1 + b3[1], a2 + b3[2], 0.0f);
        asm volatile("" ::: "memory");
    }
}

// ---------------- cdist, AMPLIFIED x5 ----------------
#define CDIST_REPS 5
__global__ __launch_bounds__(256) void cdist_kernel(const float* __restrict__ y4,
                                                    float* __restrict__ out) {
    int tx = threadIdx.x & 63;
    int ty = threadIdx.x >> 6;
    int j0 = blockIdx.x * 256 + tx * 4;
    int i0 = blockIdx.y * 64 + ty * 16;
    const float4* yv = (const float4*)y4;
    for (int rep = 0; rep < CDIST_REPS; ++rep) {
        float jx[4], jy[4], jz[4];
#pragma unroll
        for (int j = 0; j < 4; j++) {
            float4 t = yv[j0 + j];
            jx[j] = t.x; jy[j] = t.y; jz[j] = t.z;
        }
#pragma unroll
        for (int i = 0; i < 16; i++) {
            float4 ti = yv[i0 + i];
            f32x4 o;
#pragma unroll
            for (int j = 0; j < 4; j++) {
                float dx = ti.x - jx[j];
                float dy = ti.y - jy[j];
                float dz = ti.z - jz[j];
                o[j] = sqrtf(dx * dx + dy * dy + dz * dz);
            }
            __builtin_nontemporal_store(o, (f32x4*)(out + (size_t)(i0 + i) * NN + j0));
        }
        asm volatile("" ::: "memory");
    }
}

extern "C" void kernel_launch(void* const* d_in, const int* in_sizes, int n_in,
                              void* d_out, int out_size, void* d_ws, size_t ws_size,
                              hipStream_t stream) {
    const float* x   = (const float*)d_in[0];
    const int*   ei  = (const int*)d_in[1];
    const float* W_l = (const float*)d_in[2];
    const float* b_l = (const float*)d_in[3];
    const float* W_r = (const float*)d_in[4];
    const float* Wa  = (const float*)d_in[5];
    const float* ba  = (const float*)d_in[6];
    const float* W1  = (const float*)d_in[7];
    const float* b1  = (const float*)d_in[8];
    const float* W2  = (const float*)d_in[9];
    const float* b2  = (const float*)d_in[10];
    const float* W3  = (const float*)d_in[11];
    const float* b3  = (const float*)d_in[12];
    float* out = (float*)d_out;
    const int E = in_sizes[1] / 2;

    auto al = [](size_t b) { return (b + 255) & ~(size_t)255; };
    const size_t small_need = al(NN * 4) + al((NN + 1) * 4) +
                              al((size_t)E * 4) + al((size_t)NN * 16) +
                              al(512 * 512 * 2) * 2 + al(512 * 256 * 2) +
                              al(256 * 128 * 2);
    const size_t act_need = al((size_t)NN * 512 * 2) * 2 + al((size_t)NN * 512 * 2) +
                            al((size_t)NN * 256 * 2) + al((size_t)NN * 128 * 2);
    char* sbase;
    char* abase;
    if (ws_size >= small_need + act_need) {
        sbase = (char*)d_ws; abase = (char*)d_ws + small_need;
    } else if (ws_size >= small_need) {
        sbase = (char*)d_ws; abase = (char*)d_out;
    } else {
        sbase = (char*)d_out; abase = (char*)d_out + small_need;
    }
    size_t so = 0, ao = 0;
    auto carve_s = [&](size_t b) { char* p = sbase + so; so += al(b); return p; };
    auto carve_a = [&](size_t b) { char* p = abase + ao; ao += al(b); return p; };

    int*   deg     = (int*)carve_s(NN * 4);
    int*   row_ptr = (int*)carve_s((NN + 1) * 4);
    int*   csr     = (int*)carve_s((size_t)E * 4);
    float* yv      = (float*)carve_s((size_t)NN * 16);
    f16*   Wlt     = (f16*)carve_s(512 * 512 * 2);
    f16*   Wrt     = (f16*)carve_s(512 * 512 * 2);
    f16*   Wat     = (f16*)carve_s(512 * 256 * 2);
    f16*   W1t     = (f16*)carve_s(256 * 128 * 2);

    f16* x_h   = (f16*)carve_a((size_t)NN * 512 * 2);
    f16* agg_h = (f16*)carve_a((size_t)NN * 512 * 2);
    f16* h1    = (f16*)carve_a((size_t)NN * 512 * 2);
    f16* h2    = (f16*)carve_a((size_t)NN * 256 * 2);
    f16* h3    = (f16*)carve_a((size_t)NN * 128 * 2);

    // ---- prep (x24) ----
    prep_kernel<<<2048 + 256 + 256 + 128 + 32 + 32, 256, 0, stream>>>(
        x, x_h, W_l, Wlt, W_r, Wrt, Wa, Wat, W1, W1t, deg);

    // ---- CSR build (deg x32 w/ scratch=csr; scan x64; scatter x1) ----
    deg_kernel<<<(E + 255) / 256, 256, 0, stream>>>(ei, deg, csr, E);
    scan_kernel<<<1, 1024, 0, stream>>>(deg, row_ptr);
    scatter_kernel<<<(E + 255) / 256, 256, 0, stream>>>(ei, row_ptr, deg, csr, E);

    // ---- aggregation (x1) ----
    agg_kernel<<<NN / 4, 256, 0, stream>>>(x_h, row_ptr, csr, agg_h);

    // ---- MLP chain (x1) ----
    gemm_thin<256><<<dim3(2, 256), 256, 0, stream>>>(
        agg_h, Wlt, x_h, Wrt, b_l, h1, 512, 512, 1);
    gemm_thin<128><<<dim3(2, 256), 256, 0, stream>>>(
        h1, Wat, nullptr, nullptr, ba, h2, 256, 512, 1);
    gemm_thin<128><<<dim3(1, 256), 256, 0, stream>>>(
        h2, W1t, nullptr, nullptr, b1, h3, 128, 256, 1);
    // ---- tail (x20) ----
    tail_kernel<<<NN * 2 / 256, 256, 0, stream>>>(h3, W2, b2, W3, b3, yv);

    // ---- cdist (x5) ----
    cdist_kernel<<<dim3(NN / 256, NN / 64), 256, 0, stream>>>(yv, out);
}

// Round 9
// 214.171 us; speedup vs baseline: 6.7359x; 4.3228x over previous
//
#include <hip/hip_runtime.h>
#include <math.h>

#define NN 8192
#define DD 512
#define HB 64   // histogram blocks for CSR build

typedef _Float16 f16;
typedef _Float16 half8 __attribute__((ext_vector_type(8)));
typedef _Float16 half4 __attribute__((ext_vector_type(4)));
typedef float f32x4 __attribute__((ext_vector_type(4)));

typedef const __attribute__((address_space(1))) unsigned int* gptr_t;
typedef __attribute__((address_space(3))) unsigned int* lptr_t;

__device__ __forceinline__ void gload16(const void* g, void* l) {
    __builtin_amdgcn_global_load_lds((gptr_t)g, (lptr_t)l, 16, 0, 0);
}

// ---------------- CSR build, atomic-free (counting sort) ----------------
// K1: per-block LDS histogram of dst over this block's edge chunk.
__global__ __launch_bounds__(256) void hist_kernel(const int* __restrict__ ei,
                                                   int* __restrict__ locoff, int E) {
    __shared__ int h[NN];
    int b = blockIdx.x, tid = threadIdx.x;
#pragma unroll
    for (int i = 0; i < NN / 256; i++) h[i * 256 + tid] = 0;
    __syncthreads();
    int epb = (E + HB - 1) / HB;
    int e0 = b * epb, e1 = min(e0 + epb, E);
    for (int e = e0 + tid; e < e1; e += 256)
        atomicAdd(&h[ei[E + e]], 1);   // LDS atomic
    __syncthreads();
#pragma unroll
    for (int i = 0; i < NN / 256; i++) {
        int n = i * 256 + tid;
        locoff[b * NN + n] = h[n];
    }
}

// K2a: per-node exclusive prefix over the HB block counts (in place) + deg total.
__global__ __launch_bounds__(256) void offs_kernel(int* __restrict__ locoff,
                                                   int* __restrict__ deg) {
    int n = blockIdx.x * 256 + threadIdx.x;
    int s = 0;
#pragma unroll 8
    for (int b = 0; b < HB; b++) {
        int v = locoff[b * NN + n];
        locoff[b * NN + n] = s;
        s += v;
    }
    deg[n] = s;
}

// K2b: row_ptr = exclusive scan of deg (single block).
__global__ __launch_bounds__(1024) void scan_kernel(const int* __restrict__ deg,
                                                    int* __restrict__ row_ptr) {
    __shared__ int sums[1024];
    int tid = threadIdx.x;
    int base = tid * 8;
    int local[8];
    int s = 0;
#pragma unroll
    for (int i = 0; i < 8; i++) { local[i] = s; s += deg[base + i]; }
    sums[tid] = s;
    __syncthreads();
    for (int off = 1; off < 1024; off <<= 1) {
        int v = sums[tid];
        int u = (tid >= off) ? sums[tid - off] : 0;
        __syncthreads();
        sums[tid] = v + u;
        __syncthreads();
    }
    int prev = (tid == 0) ? 0 : sums[tid - 1];
#pragma unroll
    for (int i = 0; i < 8; i++) row_ptr[base + i] = prev + local[i];
    if (tid == 1023) row_ptr[NN] = sums[1023];
}

// K3: scatter via LDS cursors — no global atomics.
__global__ __launch_bounds__(256) void scatter_kernel(const int* __restrict__ ei,
                                                      const int* __restrict__ row_ptr,
                                                      const int* __restrict__ locoff,
                                                      int* __restrict__ csr, int E) {
    __shared__ int cur[NN];
    int b = blockIdx.x, tid = threadIdx.x;
#pragma unroll
    for (int i = 0; i < NN / 256; i++) {
        int n = i * 256 + tid;
        cur[n] = row_ptr[n] + locoff[b * NN + n];
    }
    __syncthreads();
    int epb = (E + HB - 1) / HB;
    int e0 = b * epb, e1 = min(e0 + epb, E);
    for (int e = e0 + tid; e < e1; e += 256) {
        int dst = ei[E + e];
        int src = ei[e];
        int pos = atomicAdd(&cur[dst], 1);   // LDS atomic
        csr[pos] = src;
    }
}

// ---------------- prep: x->f16 + weight transposes ----------------
__device__ __forceinline__ void transpose_tile(const float* __restrict__ W,
                                               f16* __restrict__ Wt,
                                               int Kw, int Nw, int bx, int by,
                                               float (*tile)[33]) {
    int n0 = bx * 32, k0 = by * 32;
    int t = threadIdx.x;
    {
        int r = t >> 3, cq = (t & 7) * 4;
        float4 v = *(const float4*)(W + (size_t)(k0 + r) * Nw + n0 + cq);
        tile[r][cq] = v.x; tile[r][cq + 1] = v.y; tile[r][cq + 2] = v.z; tile[r][cq + 3] = v.w;
    }
    __syncthreads();
    {
        int n = t >> 3, rq = (t & 7) * 4;
        half4 h;
        h[0] = (f16)tile[rq][n];     h[1] = (f16)tile[rq + 1][n];
        h[2] = (f16)tile[rq + 2][n]; h[3] = (f16)tile[rq + 3][n];
        *(half4*)(Wt + (size_t)(n0 + n) * Kw + k0 + rq) = h;
    }
}

__global__ __launch_bounds__(256) void prep_kernel(const float* __restrict__ x,
                                                   f16* __restrict__ xh,
                                                   const float* __restrict__ W_l, f16* __restrict__ Wlt,
                                                   const float* __restrict__ W_r, f16* __restrict__ Wrt,
                                                   const float* __restrict__ Wa,  f16* __restrict__ Wat,
                                                   const float* __restrict__ W1,  f16* __restrict__ W1t) {
    __shared__ float tile[32][33];
    int b = blockIdx.x;
    if (b < 2048) {
        int i = b * 256 + threadIdx.x;
        const float4* p = (const float4*)x + (size_t)i * 2;
        float4 v0 = p[0], v1 = p[1];
        half8 h;
        h[0] = (f16)v0.x; h[1] = (f16)v0.y; h[2] = (f16)v0.z; h[3] = (f16)v0.w;
        h[4] = (f16)v1.x; h[5] = (f16)v1.y; h[6] = (f16)v1.z; h[7] = (f16)v1.w;
        ((half8*)xh)[i] = h;
        return;
    }
    b -= 2048;
    if (b < 256)      { transpose_tile(W_l, Wlt, 512, 512, b & 15, b >> 4, tile); return; }
    b -= 256;
    if (b < 256)      { transpose_tile(W_r, Wrt, 512, 512, b & 15, b >> 4, tile); return; }
    b -= 256;
    if (b < 128)      { transpose_tile(Wa, Wat, 512, 256, b & 7, b >> 3, tile); return; }
    b -= 128;
    transpose_tile(W1, W1t, 256, 128, b & 3, b >> 2, tile);
}

// ---------------- mean aggregation: one wave per node, 4-edge unroll ----------------
__global__ __launch_bounds__(256) void agg_kernel(const f16* __restrict__ xh,
                                                  const int* __restrict__ row_ptr,
                                                  const int* __restrict__ csr,
                                                  f16* __restrict__ aggh) {
    int node = blockIdx.x * 4 + (threadIdx.x >> 6);
    int l = threadIdx.x & 63;
    int s = row_ptr[node], e = row_ptr[node + 1];
    const half8* xb = (const half8*)xh;
    float acc[8] = {0, 0, 0, 0, 0, 0, 0, 0};
    int p = s;
    for (; p + 4 <= e; p += 4) {
        int s0 = csr[p], s1 = csr[p + 1], s2 = csr[p + 2], s3 = csr[p + 3];
        half8 v0 = xb[(size_t)s0 * 64 + l];
        half8 v1 = xb[(size_t)s1 * 64 + l];
        half8 v2 = xb[(size_t)s2 * 64 + l];
        half8 v3 = xb[(size_t)s3 * 64 + l];
#pragma unroll
        for (int j = 0; j < 8; j++)
            acc[j] += (float)v0[j] + (float)v1[j] + (float)v2[j] + (float)v3[j];
    }
    for (; p < e; p++) {
        half8 v = xb[(size_t)csr[p] * 64 + l];
#pragma unroll
        for (int j = 0; j < 8; j++) acc[j] += (float)v[j];
    }
    float inv = 1.0f / fmaxf((float)(e - s), 1.0f);
    half8 h;
#pragma unroll
    for (int j = 0; j < 8; j++) h[j] = (f16)(acc[j] * inv);
    ((half8*)aggh)[(size_t)node * 64 + l] = h;
}

// ---------------- MFMA GEMM thin-row (round-6 version) ----------------
template<int BN>
__global__ __launch_bounds__(256) void gemm_thin(const f16* __restrict__ A1,
                                                 const f16* __restrict__ B1,
                                                 const f16* __restrict__ A2,
                                                 const f16* __restrict__ B2,
                                                 const float* __restrict__ bias,
                                                 f16* __restrict__ C,
                                                 int N, int K, int relu) {
    constexpr int BM = 32;
    constexpr int FM = 2;
    constexpr int FN = BN / 64;
    constexpr int ACH = BM / 16;
    constexpr int NCH = (BM + BN) / 16;
    __shared__ f16 As[2][BM * 32];
    __shared__ f16 Bs[2][BN * 32];

    const int tid = threadIdx.x;
    const int l = tid & 63;
    const int wid = tid >> 6;
    const int row0 = blockIdx.y * BM;
    const int col0 = blockIdx.x * BN;
    const int rowc = l >> 2;
    const int sp = l & 3;

    f32x4 acc[FM][FN];
#pragma unroll
    for (int i = 0; i < FM; i++)
#pragma unroll
        for (int j = 0; j < FN; j++)
#pragma unroll
            for (int q = 0; q < 4; q++) acc[i][j][q] = 0.0f;

    const int ktiles = K >> 5;
    const int npass = (A2 != nullptr) ? 2 : 1;
    const int nt = ktiles * npass;

    auto stage = [&](int buf, int t) {
        int pass = (t >= ktiles) ? 1 : 0;
        int kk = (t - pass * ktiles) << 5;
        const f16* Ag = pass ? A2 : A1;
        const f16* Bg = pass ? B2 : B1;
#pragma unroll
        for (int c = wid; c < NCH; c += 4) {
            bool isA = (c < ACH);
            int cc = isA ? c : c - ACH;
            int row = cc * 16 + rowc;
            int slot = sp ^ ((row >> 1) & 3);
            const f16* g;
            f16* ld;
            if (isA) {
                g = Ag + (size_t)(row0 + row) * K + kk + slot * 8;
                ld = &As[buf][cc * 512];
            } else {
                g = Bg + (size_t)(col0 + row) * K + kk + slot * 8;
                ld = &Bs[buf][cc * 512];
            }
            gload16(g, ld);
        }
    };

    stage(0, 0);
    __syncthreads();
    for (int t = 0; t < nt; ++t) {
        int cur = t & 1;
        if (t + 1 < nt) stage(cur ^ 1, t + 1);
        half8 af[FM], bf[FN];
#pragma unroll
        for (int i = 0; i < FM; i++) {
            int r = i * 16 + (l & 15);
            int off = r * 64 + ((((l >> 4) ^ ((r >> 1) & 3))) << 4);
            af[i] = *(const half8*)((const char*)As[cur] + off);
        }
#pragma unroll
        for (int j = 0; j < FN; j++) {
            int r = wid * FN * 16 + j * 16 + (l & 15);
            int off = r * 64 + ((((l >> 4) ^ ((r >> 1) & 3))) << 4);
            bf[j] = *(const half8*)((const char*)Bs[cur] + off);
        }
#pragma unroll
        for (int i = 0; i < FM; i++)
#pragma unroll
            for (int j = 0; j < FN; j++)
                acc[i][j] = __builtin_amdgcn_mfma_f32_16x16x32_f16(af[i], bf[j], acc[i][j], 0, 0, 0);
        __syncthreads();
    }

#pragma unroll
    for (int i = 0; i < FM; i++)
#pragma unroll
        for (int j = 0; j < FN; j++) {
            int row = row0 + i * 16 + ((l >> 4) << 2);
            int col = col0 + wid * FN * 16 + j * 16 + (l & 15);
            float bv = bias[col];
#pragma unroll
            for (int q = 0; q < 4; q++) {
                float v = acc[i][j][q] + bv;
                if (relu) v = fmaxf(v, 0.0f);
                C[(size_t)(row + q) * N + col] = (f16)v;
            }
        }
}

// ---------------- fused tail: h4 = relu(h3@W2+b2); y = h4@W3+b3 ----------------
__global__ __launch_bounds__(256) void tail_kernel(const f16* __restrict__ h3,
                                                   const float* __restrict__ W2,
                                                   const float* __restrict__ b2,
                                                   const float* __restrict__ W3,
                                                   const float* __restrict__ b3,
                                                   float* __restrict__ y) {
    int tid = blockIdx.x * 256 + threadIdx.x;
    int row = tid >> 1;
    int c0 = (tid & 1) * 32;
    float acc[32];
#pragma unroll
    for (int c = 0; c < 32; c++) acc[c] = b2[c0 + c];
    const half8* hr = (const half8*)(h3 + (size_t)row * 128);
#pragma unroll
    for (int g = 0; g < 16; g++) {
        half8 hv = hr[g];
#pragma unroll
        for (int j = 0; j < 8; j++) {
            float v = (float)hv[j];
            const float4* w = (const float4*)(W2 + (size_t)(g * 8 + j) * 64 + c0);
#pragma unroll
            for (int q = 0; q < 8; q++) {
                float4 wv = w[q];
                acc[q * 4 + 0] += v * wv.x;
                acc[q * 4 + 1] += v * wv.y;
                acc[q * 4 + 2] += v * wv.z;
                acc[q * 4 + 3] += v * wv.w;
            }
        }
    }
    float a0 = 0.f, a1 = 0.f, a2 = 0.f;
#pragma unroll
    for (int c = 0; c < 32; c++) {
        float v = fmaxf(acc[c], 0.0f);
        int k = c0 + c;
        a0 += v * W3[k * 3 + 0];
        a1 += v * W3[k * 3 + 1];
        a2 += v * W3[k * 3 + 2];
    }
    a0 += __shfl_xor(a0, 1);
    a1 += __shfl_xor(a1, 1);
    a2 += __shfl_xor(a2, 1);
    if ((tid & 1) == 0)
        ((float4*)y)[row] = make_float4(a0 + b3[0], a1 + b3[1], a2 + b3[2], 0.0f);
}

// ---------------- cdist ----------------
__global__ __launch_bounds__(256) void cdist_kernel(const float* __restrict__ y4,
                                                    float* __restrict__ out) {
    int tx = threadIdx.x & 63;
    int ty = threadIdx.x >> 6;
    int j0 = blockIdx.x * 256 + tx * 4;
    int i0 = blockIdx.y * 64 + ty * 16;
    float jx[4], jy[4], jz[4];
    const float4* yv = (const float4*)y4;
#pragma unroll
    for (int j = 0; j < 4; j++) {
        float4 t = yv[j0 + j];
        jx[j] = t.x; jy[j] = t.y; jz[j] = t.z;
    }
#pragma unroll
    for (int i = 0; i < 16; i++) {
        float4 ti = yv[i0 + i];
        f32x4 o;
#pragma unroll
        for (int j = 0; j < 4; j++) {
            float dx = ti.x - jx[j];
            float dy = ti.y - jy[j];
            float dz = ti.z - jz[j];
            o[j] = sqrtf(dx * dx + dy * dy + dz * dz);
        }
        __builtin_nontemporal_store(o, (f32x4*)(out + (size_t)(i0 + i) * NN + j0));
    }
}

extern "C" void kernel_launch(void* const* d_in, const int* in_sizes, int n_in,
                              void* d_out, int out_size, void* d_ws, size_t ws_size,
                              hipStream_t stream) {
    const float* x   = (const float*)d_in[0];
    const int*   ei  = (const int*)d_in[1];
    const float* W_l = (const float*)d_in[2];
    const float* b_l = (const float*)d_in[3];
    const float* W_r = (const float*)d_in[4];
    const float* Wa  = (const float*)d_in[5];
    const float* ba  = (const float*)d_in[6];
    const float* W1  = (const float*)d_in[7];
    const float* b1  = (const float*)d_in[8];
    const float* W2  = (const float*)d_in[9];
    const float* b2  = (const float*)d_in[10];
    const float* W3  = (const float*)d_in[11];
    const float* b3  = (const float*)d_in[12];
    float* out = (float*)d_out;
    const int E = in_sizes[1] / 2;

    auto al = [](size_t b) { return (b + 255) & ~(size_t)255; };
    const size_t small_need = al(NN * 4) + al((NN + 1) * 4) +
                              al((size_t)E * 4) + al((size_t)HB * NN * 4) +
                              al((size_t)NN * 16) +
                              al(512 * 512 * 2) * 2 + al(512 * 256 * 2) +
                              al(256 * 128 * 2);
    const size_t act_need = al((size_t)NN * 512 * 2) * 2 + al((size_t)NN * 512 * 2) +
                            al((size_t)NN * 256 * 2) + al((size_t)NN * 128 * 2);
    char* sbase;
    char* abase;
    if (ws_size >= small_need + act_need) {
        sbase = (char*)d_ws; abase = (char*)d_ws + small_need;
    } else if (ws_size >= small_need) {
        sbase = (char*)d_ws; abase = (char*)d_out;
    } else {
        sbase = (char*)d_out; abase = (char*)d_out + small_need;
    }
    size_t so = 0, ao = 0;
    auto carve_s = [&](size_t b) { char* p = sbase + so; so += al(b); return p; };
    auto carve_a = [&](size_t b) { char* p = abase + ao; ao += al(b); return p; };

    int*   deg     = (int*)carve_s(NN * 4);
    int*   row_ptr = (int*)carve_s((NN + 1) * 4);
    int*   csr     = (int*)carve_s((size_t)E * 4);
    int*   locoff  = (int*)carve_s((size_t)HB * NN * 4);
    float* yv      = (float*)carve_s((size_t)NN * 16);
    f16*   Wlt     = (f16*)carve_s(512 * 512 * 2);
    f16*   Wrt     = (f16*)carve_s(512 * 512 * 2);
    f16*   Wat     = (f16*)carve_s(512 * 256 * 2);
    f16*   W1t     = (f16*)carve_s(256 * 128 * 2);

    f16* x_h   = (f16*)carve_a((size_t)NN * 512 * 2);
    f16* agg_h = (f16*)carve_a((size_t)NN * 512 * 2);
    f16* h1    = (f16*)carve_a((size_t)NN * 512 * 2);
    f16* h2    = (f16*)carve_a((size_t)NN * 256 * 2);
    f16* h3    = (f16*)carve_a((size_t)NN * 128 * 2);

    // ---- prep (x cvt + weight transposes) ----
    prep_kernel<<<2048 + 256 + 256 + 128 + 32, 256, 0, stream>>>(
        x, x_h, W_l, Wlt, W_r, Wrt, Wa, Wat, W1, W1t);

    // ---- CSR build (atomic-free counting sort) ----
    hist_kernel<<<HB, 256, 0, stream>>>(ei, locoff, E);
    offs_kernel<<<NN / 256, 256, 0, stream>>>(locoff, deg);
    scan_kernel<<<1, 1024, 0, stream>>>(deg, row_ptr);
    scatter_kernel<<<HB, 256, 0, stream>>>(ei, row_ptr, locoff, csr, E);

    // ---- aggregation ----
    agg_kernel<<<NN / 4, 256, 0, stream>>>(x_h, row_ptr, csr, agg_h);

    // ---- MLP chain (thin-row MFMA) ----
    gemm_thin<256><<<dim3(2, 256), 256, 0, stream>>>(
        agg_h, Wlt, x_h, Wrt, b_l, h1, 512, 512, 1);
    gemm_thin<128><<<dim3(2, 256), 256, 0, stream>>>(
        h1, Wat, nullptr, nullptr, ba, h2, 256, 512, 1);
    gemm_thin<128><<<dim3(1, 256), 256, 0, stream>>>(
        h2, W1t, nullptr, nullptr, b1, h3, 128, 256, 1);
    // h4 + y fused (VALU)
    tail_kernel<<<NN * 2 / 256, 256, 0, stream>>>(h3, W2, b2, W3, b3, yv);

    // ---- cdist ----
    cdist_kernel<<<dim3(NN / 256, NN / 64), 256, 0, stream>>>(yv, out);
}